// Round 13
// baseline (361.413 us; speedup 1.0000x reference)
//
#include <hip/hip_runtime.h>
#include <hip/hip_bf16.h>

#define NN 50000
#define NE 800000
#define NG 50
#define NSL 16    // pool slices per graph
#define NSCB 196  // scan blocks (196*256 = 50176 >= NN+1 nodes)
#define NNP (NSCB * 256)        // padded node count 50176
#define NC8 (NNP * 8)           // cnt8/excl8 size 401408

typedef unsigned short u16;
typedef unsigned int u32;
typedef __attribute__((ext_vector_type(8))) short short8;
typedef __attribute__((ext_vector_type(4))) float float4v;
typedef __attribute__((ext_vector_type(2))) float f32x2;

__device__ __forceinline__ float b2f(u16 u) {
    union { u32 i; float f; } v; v.i = ((u32)u) << 16; return v.f;
}
__device__ __forceinline__ u16 f2b(float f) {
    union { float f; u32 i; } v; v.f = f;
    u32 i = v.i;
    return (u16)((i + 0x7FFFu + ((i >> 16) & 1u)) >> 16);
}
__device__ __forceinline__ float lo16f(u32 u) { union { u32 i; float f; } v; v.i = u << 16; return v.f; }
__device__ __forceinline__ float hi16f(u32 u) { union { u32 i; float f; } v; v.i = u & 0xffff0000u; return v.f; }

// ---------------- init + detect + gaussian-coef precompute ----------------
struct SgP { const float* mu[4]; const float* sg[4]; };
__global__ void k_init(const int* __restrict__ ei_raw, int* flag,
                       int* cnt8, int* startg, int* endg, SgP S, float* __restrict__ gcoef,
                       int* dcnt) {
    __shared__ int cs[256];
    int i = blockIdx.x * blockDim.x + threadIdx.x;
    if (i < NC8) cnt8[i] = 0;
    if (i < NG) { startg[i] = 0x7fffffff; endg[i] = 0; }
    if (blockIdx.x == 2 && threadIdx.x < 64) dcnt[threadIdx.x] = 0;
    if (blockIdx.x == 0 && threadIdx.x < 64) {
        int t = threadIdx.x;          // [l][k][d] coef then [l][k][d] mu
        int l = (t >> 3) & 3, kd = t & 7;
        if (t < 32) {
            float s = S.sg[l][kd];
            gcoef[t] = -0.5f / (1e-15f + s * s);
        } else {
            gcoef[t] = S.mu[l][kd];   // gcoef[32 + l*8 + kd]
        }
    }
    if (blockIdx.x == 1) {
        int t = threadIdx.x;
        cs[t] = (ei_raw[2 * t + 1] == 0) ? 1 : 0;   // flag=1 <=> int64 edge_index
        __syncthreads();
        for (int d = 128; d > 0; d >>= 1) {
            if (t < d) cs[t] += cs[t + d];
            __syncthreads();
        }
        if (t == 0) *flag = (cs[0] >= 128) ? 1 : 0;
    }
}

// ---------------- cvt + prep mega-fusion: rank-hist(2e/thr,vec) | x2b(vec4) | wprep | bounds ----------------
// R13: hist processes 2 edges/thread with int4 (int64 input) / int2 (int32) loads — fully
// dense lines instead of stride-8B scalar, half the blocks; rank pair packed into one u32.
// Block map: [0,1563) hist | [1563,4688) x2b | [4688,5008) wprep | [5008,5204) bounds.
struct WParams { const float* g[4]; const float* rw[4]; };
__global__ void k_cvtprep(const int* __restrict__ ei_raw, const int* __restrict__ batch_raw,
                          const int* __restrict__ flag, int* cnt8, u16* __restrict__ rank,
                          const float* __restrict__ x, u16* __restrict__ xb,
                          WParams P, u16* __restrict__ bsw,
                          int* startg, int* endg) {
    int b = blockIdx.x, t = threadIdx.x;
    if (b < 1563) {                        // rank histogram: color = src/6250 (src-range shard)
        int g = b * 256 + t;
        int e = g * 2;
        if (e < NE) {
            int w = *flag;
            int s0, s1, d0, d1;
            if (w) {
                int4 sv = *(const int4*)(ei_raw + (size_t)4 * g);
                int4 dv = *(const int4*)(ei_raw + (size_t)2 * NE + (size_t)4 * g);
                s0 = sv.x; s1 = sv.z; d0 = dv.x; d1 = dv.z;
            } else {
                int2 sv = *(const int2*)(ei_raw + (size_t)2 * g);
                int2 dv = *(const int2*)(ei_raw + (size_t)NE + (size_t)2 * g);
                s0 = sv.x; s1 = sv.y; d0 = dv.x; d1 = dv.y;
            }
            u32 r0 = (u32)atomicAdd(&cnt8[d0 * 8 + s0 / 6250], 1);
            u32 r1 = (u32)atomicAdd(&cnt8[d1 * 8 + s1 / 6250], 1);
            *(u32*)(rank + e) = (r0 & 0xffffu) | (r1 << 16);
        }
    } else if (b < 4688) {                 // x2b vec4: 800000 threads x 4 elems = NN*64
        int i = (b - 1563) * 256 + t;      // exact fit: 3125*256*4 == NN*64
        float4 v = *(const float4*)(x + (size_t)i * 4);
        u32 lo = (u32)f2b(v.x) | ((u32)f2b(v.y) << 16);
        u32 hi = (u32)f2b(v.z) | ((u32)f2b(v.w) << 16);
        uint2 pk; pk.x = lo; pk.y = hi;
        *(uint2*)(xb + (size_t)i * 4) = pk;
    } else if (b < 5008) {                 // wprep: 4*20480 ids (320 blocks exact)
        int id = (b - 4688) * 256 + t;
        if (id < 4 * 20480) {
            int l = id / 20480, r = id % 20480;
            int j = r & 7, lane = (r >> 3) & 63, ctkt = r >> 9;
            int ct = ctkt & 3, kt = ctkt >> 2;
            int k = kt * 32 + (lane >> 4) * 8 + j;
            int n = ct * 16 + (lane & 15);
            float v;
            if (k < 256) v = P.g[l][(k & 63) * 256 + (k >> 6) * 64 + n];
            else         v = P.rw[l][(k - 256) * 64 + n];
            bsw[id] = f2b(v);
        }
    } else {                               // bounds: boundary scan on raw batch
        int n = (b - 5008) * 256 + t;
        if (n >= NN) return;
        int w = *flag;
        int bb = w ? batch_raw[2 * n] : batch_raw[n];
        if (n == 0) {
            startg[bb] = 0;
        } else {
            int bp = w ? batch_raw[2 * (n - 1)] : batch_raw[n - 1];
            if (bp != bb) { startg[bb] = n; endg[bp] = n; }
        }
        if (n == NN - 1) endg[bb] = NN;
    }
}

// ---------------- scan A: per-node color scan + degree-bucket rank (two-level) ----------------
__global__ __launch_bounds__(256) void k_scanA(const int* __restrict__ cnt8, int* __restrict__ excl8,
                                               int* __restrict__ bsum, int* dcnt, int* __restrict__ pnr) {
    __shared__ int s[256];
    __shared__ int hcnt[64];
    __shared__ int hbase[64];
    int t = threadIdx.x, b = blockIdx.x;
    int n = b * 256 + t;                  // node (padded)
    uint4 c0 = *(const uint4*)(cnt8 + (size_t)n * 8);
    uint4 c1 = *(const uint4*)(cnt8 + (size_t)n * 8 + 4);
    int v = c0.x + c0.y + c0.z + c0.w + c1.x + c1.y + c1.z + c1.w;
    if (t < 64) hcnt[t] = 0;
    s[t] = v; __syncthreads();
    for (int d = 1; d < 256; d <<= 1) {
        int x = s[t];
        int y = (t >= d) ? s[t - d] : 0;
        __syncthreads();
        s[t] = x + y;
        __syncthreads();
    }
    int run = s[t] - v;                   // exclusive prefix within block
    uint4 e0, e1;
    e0.x = run;            e0.y = run + c0.x;
    e0.z = e0.y + c0.y;    e0.w = e0.z + c0.z;
    e1.x = e0.w + c0.w;    e1.y = e1.x + c1.x;
    e1.z = e1.y + c1.y;    e1.w = e1.z + c1.z;
    *(uint4*)(excl8 + (size_t)n * 8) = e0;
    *(uint4*)(excl8 + (size_t)n * 8 + 4) = e1;
    if (t == 255) bsum[b] = s[255];
    // --- degree bucket rank ---
    int nb;
    if (n < NN) { nb = (v + 3) >> 2; if (nb > 62) nb = 62; } else nb = 63;
    int lrank = atomicAdd(&hcnt[nb], 1);
    __syncthreads();
    if (t < 64) hbase[t] = atomicAdd(&dcnt[t], hcnt[t]);
    __syncthreads();
    pnr[n] = (nb << 20) | (hbase[nb] + lrank);
}

// ---------------- scan B+C fused + perm scatter ----------------
__global__ __launch_bounds__(256) void k_scanBC(const int* __restrict__ excl8,
                                                const int* __restrict__ bsum,
                                                int* __restrict__ off8,
                                                const int* __restrict__ dcnt,
                                                const int* __restrict__ pnr,
                                                int* __restrict__ perm) {
    __shared__ int s[256];
    __shared__ int dsc[64];
    int t = threadIdx.x, b = blockIdx.x;
    int v = (t < NSCB) ? bsum[t] : 0;
    s[t] = v;
    if (t < 64) dsc[t] = dcnt[t];
    __syncthreads();
    for (int d = 1; d < 256; d <<= 1) {
        int x = s[t];
        int y = (t >= d) ? s[t - d] : 0;
        __syncthreads();
        s[t] = x + y;
        __syncthreads();
    }
    int ebase = (b == 0) ? 0 : s[b - 1];
    int n = b * 256 + t;
    uint4 e0 = *(const uint4*)(excl8 + (size_t)n * 8);
    uint4 e1 = *(const uint4*)(excl8 + (size_t)n * 8 + 4);
    e0.x += ebase; e0.y += ebase; e0.z += ebase; e0.w += ebase;
    e1.x += ebase; e1.y += ebase; e1.z += ebase; e1.w += ebase;
    *(uint4*)(off8 + (size_t)n * 8) = e0;
    *(uint4*)(off8 + (size_t)n * 8 + 4) = e1;
    // --- exclusive scan of 64 bucket counts (identical in every block) + scatter perm ---
    if (t == 0) {
        int runb = 0;
        for (int i = 0; i < 64; i++) { int c = dsc[i]; dsc[i] = runb; runb += c; }
    }
    __syncthreads();
    int pv = pnr[n];
    perm[dsc[pv >> 20] + (pv & 0xFFFFF)] = n;
}

// ---------------- scatter: 2 edges/thread, ONE 8B record per edge: {src*128, a0q|a1q<<16} ----------------
// R13: rec8.x stores the BYTE offset (src*128) so aggemm's gather needs no 64-bit shift.
// Vectorized int4/int2 edge reads (see cvtprep); attrs read as float4 pairs.
__global__ void k_scatter(const int* __restrict__ ei_raw, const int* __restrict__ flag,
                          const int* __restrict__ off8, const u16* __restrict__ rank,
                          const float2* __restrict__ eattr2,
                          uint2* __restrict__ rec8) {
    int g = blockIdx.x * blockDim.x + threadIdx.x;
    int e = g * 2;
    if (e >= NE) return;
    int w = *flag;
    int s0, s1, d0, d1;
    if (w) {
        int4 sv = *(const int4*)(ei_raw + (size_t)4 * g);
        int4 dv = *(const int4*)(ei_raw + (size_t)2 * NE + (size_t)4 * g);
        s0 = sv.x; s1 = sv.z; d0 = dv.x; d1 = dv.z;
    } else {
        int2 sv = *(const int2*)(ei_raw + (size_t)2 * g);
        int2 dv = *(const int2*)(ei_raw + (size_t)NE + (size_t)2 * g);
        s0 = sv.x; s1 = sv.y; d0 = dv.x; d1 = dv.y;
    }
    u32 rr = *(const u32*)(rank + e);
    float4 at = *(const float4*)(eattr2 + e);
    int slot0 = off8[d0 * 8 + s0 / 6250] + (int)(rr & 0xffffu);
    int slot1 = off8[d1 * 8 + s1 / 6250] + (int)(rr >> 16);
    u32 q0 = (u32)(fminf(fmaxf(at.x, 0.f), 1.f) * 65535.f + 0.5f);
    u32 q1 = (u32)(fminf(fmaxf(at.y, 0.f), 1.f) * 65535.f + 0.5f);
    u32 q2 = (u32)(fminf(fmaxf(at.z, 0.f), 1.f) * 65535.f + 0.5f);
    u32 q3 = (u32)(fminf(fmaxf(at.w, 0.f), 1.f) * 65535.f + 0.5f);
    uint2 r0; r0.x = (u32)s0 * 128u; r0.y = q0 | (q1 << 16);
    uint2 r1; r1.x = (u32)s1 * 128u; r1.y = q2 | (q3 << 16);
    rec8[slot0] = r0;
    rec8[slot1] = r1;
}

// ---------------- weights: once-per-edge gaussian weights from rec8, fully coalesced ----------------
__global__ __launch_bounds__(256) void k_wgts(const uint2* __restrict__ rec8,
                                              const float* __restrict__ gcoef,
                                              uint2* __restrict__ agw) {
    int j = blockIdx.x * blockDim.x + threadIdx.x;
    if (j >= NE) return;
    uint2 r = rec8[j];
    float a0 = (float)(r.y & 0xffffu) * (1.0f / 65535.0f);
    float a1 = (float)(r.y >> 16) * (1.0f / 65535.0f);
#pragma unroll
    for (int l = 0; l < 4; l++) {
        u16 wq[4];
#pragma unroll
        for (int k = 0; k < 4; k++) {
            float m0 = gcoef[32 + l * 8 + 2 * k], m1 = gcoef[32 + l * 8 + 2 * k + 1];
            float c0 = gcoef[l * 8 + 2 * k],      c1 = gcoef[l * 8 + 2 * k + 1];
            float d0 = a0 - m0, d1 = a1 - m1;
            float t = d0 * d0 * c0 + d1 * d1 * c1;   // t <= 0, c includes -0.5
            wq[k] = f2b(__expf(t));
        }
        uint2 o;
        o.x = (u32)wq[0] | ((u32)wq[1] << 16);
        o.y = (u32)wq[2] | ((u32)wq[3] << 16);
        agw[(size_t)l * NE + j] = o;
    }
}

// ---------------- fused aggregation + GEMM (R4 config + deg-sorted perm + R13 fast path) ----------------
// R13: (a) rec8.x is a byte offset -> gather addr is one add; (b) full batches (bt < deg>>2)
// skip the clamp/cndmask tail logic entirely — after deg-sorting the branch is usually
// wave-uniform, so the masked path executes at most once per node.
#define LDA 328  // 320 + 8 u16 pad -> rows 656B, 16B aligned
#define ROWS 32
__global__ __launch_bounds__(512, 8) void k_aggemm(const u16* __restrict__ xin,
                                                   const uint2* __restrict__ rec8,
                                                   const uint2* __restrict__ agw,
                                                   const int* __restrict__ off8,
                                                   const int* __restrict__ perm,
                                                   const u16* __restrict__ bsw,
                                                   const float* __restrict__ bias,
                                                   u16* __restrict__ xout,
                                                   const u16* __restrict__ xadd,
                                                   u16* __restrict__ x3out) {
    __shared__ u16 As[ROWS * LDA];
    int t = threadIdx.x;
    int rbase = blockIdx.x * ROWS;
    int wave = t >> 6, lane = t & 63;
    int sub = lane >> 4;      // node sub-group 0..3
    int f = lane & 15;        // feature quad: features 4f..4f+3

    // stage the 32 xin rows (concat part, cols 256..319) — row-gathered via perm
    if (t < 256) {
        int row = t >> 3, pos = t & 7;
        int grow = perm[rbase + row];
        uint4 v = make_uint4(0, 0, 0, 0);
        if (grow < NN) v = *(const uint4*)(xin + (size_t)grow * 64 + pos * 8);
        *(uint4*)(&As[row * LDA + 256 + pos * 8]) = v;
    }

    // ---- phase A: each 16-lane sub-group aggregates its node into As[row][0..255] ----
    {
        int row = (wave << 2) + sub;
        int wid = perm[rbase + row];      // deg-sorted node id; pads (>=NN) have beg==end
        int beg = off8[wid * 8], end = off8[wid * 8 + 8];
        int endm1 = end - 1;
        f32x2 acc[4][2];                  // [k][pair]: this lane's feats 4f..4f+3, all 4 k's
#pragma unroll
        for (int k = 0; k < 4; k++) {
            acc[k][0] = (f32x2){0.f, 0.f};
            acc[k][1] = (f32x2){0.f, 0.f};
        }
        int deg = end - beg;
        int nb = (deg + 3) >> 2;          // 4 edges per batch per node
        int nbfull = deg >> 2;            // batches with no tail masking
        for (int bt = 0; bt < nb; bt++) {
            int j0 = beg + bt * 4;
            u32 s[4]; uint2 wv[4];
            if (bt < nbfull) {            // fast path: all 4 edges valid
#pragma unroll
                for (int u = 0; u < 4; u++) {
                    int j = j0 + u;
                    s[u] = rec8[j].x;
                    wv[u] = agw[j];
                }
            } else {                      // tail batch (at most one per node)
#pragma unroll
                for (int u = 0; u < 4; u++) {
                    int j = j0 + u;
                    int jc = j < endm1 ? j : endm1;
                    bool ok = j < end;
                    s[u] = rec8[jc].x;
                    uint2 w = agw[jc];
                    wv[u].x = ok ? w.x : 0u;   // zero weight kills tail contribution
                    wv[u].y = ok ? w.y : 0u;
                }
            }
            uint2 xr[4];
#pragma unroll
            for (int u = 0; u < 4; u++)       // phase 2: all x gathers issue together
                xr[u] = *(const uint2*)((const char*)xin + (size_t)s[u] + f * 8);
#pragma unroll
            for (int u = 0; u < 4; u++) {     // phase 3: FMAs (weights pre-packed bf16)
                f32x2 x01, x23;
                x01.x = lo16f(xr[u].x); x01.y = hi16f(xr[u].x);
                x23.x = lo16f(xr[u].y); x23.y = hi16f(xr[u].y);
                float w0 = lo16f(wv[u].x), w1 = hi16f(wv[u].x);
                float w2 = lo16f(wv[u].y), w3 = hi16f(wv[u].y);
                acc[0][0] += w0 * x01; acc[0][1] += w0 * x23;
                acc[1][0] += w1 * x01; acc[1][1] += w1 * x23;
                acc[2][0] += w2 * x01; acc[2][1] += w2 * x23;
                acc[3][0] += w3 * x01; acc[3][1] += w3 * x23;
            }
        }
        float sc = 1.0f / (float)(deg > 1 ? deg : 1);
#pragma unroll
        for (int k = 0; k < 4; k++) {
            u16 o0 = f2b(acc[k][0].x * sc), o1 = f2b(acc[k][0].y * sc);
            u16 o2 = f2b(acc[k][1].x * sc), o3 = f2b(acc[k][1].y * sc);
            uint2 pk;
            pk.x = (u32)o0 | ((u32)o1 << 16);
            pk.y = (u32)o2 | ((u32)o3 << 16);
            *(uint2*)(&As[row * LDA + k * 64 + f * 4]) = pk;   // k-major [k*64+feat]
        }
    }
    __syncthreads();

    // ---- phase B: xout = lrelu(As(32,320) @ Wcat(320,64) + b); opt x3 = x0 + xout ----
    // 8 waves -> one 16x16 C tile each: rt = wave&1 (row tile), ct = wave>>1 (col tile)
    int lr = lane & 15, lg = lane >> 4;
    int rt = wave & 1;
    int ct = wave >> 1;
    const u16* ar = &As[(rt * 16 + lr) * LDA + lg * 8];
    const uint4* bp = (const uint4*)bsw;
    float4v acc0 = {0.f, 0.f, 0.f, 0.f};
    for (int kt = 0; kt < 10; kt++) {
        short8 a  = *(const short8*)(ar + kt * 32);
        short8 b0 = *(const short8*)(bp + (kt * 4 + ct) * 64 + lane);
        acc0 = __builtin_amdgcn_mfma_f32_16x16x32_bf16(a, b0, acc0, 0, 0, 0);
    }
    {
        int col = ct * 16 + lr;
        float bv = bias[col];
#pragma unroll
        for (int reg = 0; reg < 4; reg++) {
            int grow = perm[rbase + rt * 16 + lg * 4 + reg];  // C/D: row=(lane>>4)*4+reg
            if (grow < NN) {
                float v = acc0[reg] + bv;
                v = v > 0.f ? v : 0.01f * v;
                xout[(size_t)grow * 64 + col] = f2b(v);
                if (x3out) {
                    float s2 = v + b2f(xadd[(size_t)grow * 64 + col]);
                    x3out[(size_t)grow * 64 + col] = f2b(s2);
                }
            }
        }
    }
}

// ---------------- pool stage 1: partial max over node slice, concat [x4,x1,x2,x3] ----------------
__global__ __launch_bounds__(256) void k_pool1(const u16* __restrict__ x4, const u16* __restrict__ x1,
                                               const u16* __restrict__ x2, const u16* __restrict__ x3,
                                               const int* __restrict__ startg, const int* __restrict__ endg,
                                               float* __restrict__ partial) {
    int g = blockIdx.x, sl = blockIdx.y;
    int c = threadIdx.x;
    const u16* arr = (c < 64) ? x4 : (c < 128) ? x1 : (c < 192) ? x2 : x3;
    int h = c & 63;
    int s = startg[g], e = endg[g];
    int len = e - s;
    int chunk = (len + NSL - 1) / NSL;
    int s0 = s + sl * chunk;
    int e0 = s0 + chunk; if (e0 > e) e0 = e;
    float m = -3.4e38f;
    for (int n = s0; n < e0; n++) {
        float v = b2f(arr[(size_t)n * 64 + h]);
        m = v > m ? v : m;
    }
    partial[((size_t)g * NSL + sl) * 256 + c] = m;
}

// ---------------- final MLP fused with pool stage 2 (256 thr, split-j reduce) ----------------
__global__ __launch_bounds__(256) void k_final(const float* __restrict__ partial, const float* __restrict__ w1,
                        const float* __restrict__ b1, const float* __restrict__ gamma,
                        const float* __restrict__ beta, const float* __restrict__ w2,
                        const float* __restrict__ b2v, float* __restrict__ out) {
    __shared__ float pld[256];
    __shared__ float part[256];
    __shared__ float zsh[64];
    int g = blockIdx.x, t = threadIdx.x;
    int h = t & 63, jq = t >> 6;
    {
        float m = -3.4e38f;
#pragma unroll
        for (int sl = 0; sl < NSL; sl++) {
            float v = partial[((size_t)g * NSL + sl) * 256 + t];
            m = v > m ? v : m;
        }
        pld[t] = m;
    }
    __syncthreads();
    float z = 0.f;
    for (int j = jq * 64; j < jq * 64 + 64; j++) z += pld[j] * w1[j * 64 + h];
    part[t] = z;
    __syncthreads();
    if (t < 64) {
        float zz = b1[t] + part[t] + part[64 + t] + part[128 + t] + part[192 + t];
        zz = zz * 0.9999950000374997f * gamma[t] + beta[t];  // /sqrt(1+1e-5)
        zz = zz > 0.f ? zz : 0.f;
        zsh[t] = zz;
    }
    __syncthreads();
    if (t < 10) {
        float o = b2v[t];
        for (int k = 0; k < 64; k++) o += zsh[k] * w2[k * 10 + t];
        out[g * 10 + t] = o;   // fp32 output
    }
}

extern "C" void kernel_launch(void* const* d_in, const int* in_sizes, int n_in,
                              void* d_out, int out_size, void* d_ws, size_t ws_size,
                              hipStream_t stream) {
    const float* x_in    = (const float*)d_in[0];
    const int* ei_raw    = (const int*)d_in[1];
    const int* batch_raw = (const int*)d_in[2];
    const float* eattr   = (const float*)d_in[3];

    const float *g_[4], *mu_[4], *sg_[4], *rw_[4], *b_[4];
    for (int i = 0; i < 4; i++) {
        g_[i]  = (const float*)d_in[4 + 5 * i + 0];
        mu_[i] = (const float*)d_in[4 + 5 * i + 1];
        sg_[i] = (const float*)d_in[4 + 5 * i + 2];
        rw_[i] = (const float*)d_in[4 + 5 * i + 3];
        b_[i]  = (const float*)d_in[4 + 5 * i + 4];
    }
    const float* w_mlp1 = (const float*)d_in[24];
    const float* b_mlp1 = (const float*)d_in[25];
    const float* bn_g   = (const float*)d_in[26];
    const float* bn_b   = (const float*)d_in[27];
    const float* w_mlp2 = (const float*)d_in[28];
    const float* b_mlp2 = (const float*)d_in[29];
    float* out = (float*)d_out;

    // workspace carve-up (~51 MB)
    char* ws = (char*)d_ws;
    size_t o = 0;
    auto take = [&](size_t bytes) { size_t r = o; o += (bytes + 255) & ~(size_t)255; return r; };
    int*    flag     = (int*)(ws + take(4));
    float*  gcoef    = (float*)(ws + take(64 * 4));
    int*    dcnt     = (int*)(ws + take(64 * 4));
    u16*    rank     = (u16*)(ws + take((size_t)NE * 2));
    int*    cnt8     = (int*)(ws + take((size_t)NC8 * 4));
    int*    excl8    = (int*)(ws + take((size_t)NC8 * 4));
    int*    off8     = (int*)(ws + take((size_t)(NC8 + 8) * 4));
    int*    bsum     = (int*)(ws + take((size_t)NSCB * 4));
    int*    pnr      = (int*)(ws + take((size_t)NNP * 4));
    int*    perm     = (int*)(ws + take((size_t)NNP * 4));
    uint2*  rec8     = (uint2*)(ws + take((size_t)NE * 8));
    uint2*  agw      = (uint2*)(ws + take((size_t)4 * NE * 8));
    u16*    xb       = (u16*)(ws + take((size_t)NN * 64 * 2));
    u16*    x0       = (u16*)(ws + take((size_t)NN * 64 * 2));
    u16*    x1       = (u16*)(ws + take((size_t)NN * 64 * 2));
    u16*    x2       = (u16*)(ws + take((size_t)NN * 64 * 2));
    u16*    x3       = (u16*)(ws + take((size_t)NN * 64 * 2));
    u16*    x4       = (u16*)(ws + take((size_t)NN * 64 * 2));
    u16*    bsw      = (u16*)(ws + take((size_t)4 * 320 * 64 * 2));
    float*  partial  = (float*)(ws + take((size_t)NG * NSL * 256 * 4));
    int*    startg   = (int*)(ws + take(NG * 4));
    int*    endg     = (int*)(ws + take(NG * 4));
    (void)ws_size; (void)in_sizes; (void)n_in; (void)out_size;

    SgP SP;
    for (int i = 0; i < 4; i++) { SP.mu[i] = mu_[i]; SP.sg[i] = sg_[i]; }
    k_init<<<dim3((NC8 + 255) / 256), dim3(256), 0, stream>>>(ei_raw, flag, cnt8, startg, endg, SP, gcoef, dcnt);

    WParams WP;
    for (int i = 0; i < 4; i++) { WP.g[i] = g_[i]; WP.rw[i] = rw_[i]; }
    k_cvtprep<<<dim3(5204), dim3(256), 0, stream>>>(
        ei_raw, batch_raw, flag, cnt8, rank, x_in, xb, WP, bsw, startg, endg);

    k_scanA<<<dim3(NSCB), dim3(256), 0, stream>>>(cnt8, excl8, bsum, dcnt, pnr);
    k_scanBC<<<dim3(NSCB), dim3(256), 0, stream>>>(excl8, bsum, off8, dcnt, pnr, perm);
    k_scatter<<<dim3(1563), dim3(256), 0, stream>>>(
        ei_raw, flag, off8, rank, (const float2*)eattr, rec8);
    k_wgts<<<dim3(NE / 256), dim3(256), 0, stream>>>(rec8, gcoef, agw);

    const int agGrid = NNP / ROWS;         // 1568 blocks over deg-sorted perm
    const u16* lin[4]  = {xb, x0, x1, x3};
    u16*       lout[4] = {x0, x1, x2, x4};
    for (int l = 0; l < 4; l++) {
        k_aggemm<<<dim3(agGrid), dim3(512), 0, stream>>>(
            lin[l], rec8, agw + (size_t)l * NE, off8, perm,
            bsw + (size_t)l * 20480, b_[l], lout[l],
            (l == 2) ? x0 : (const u16*)nullptr,
            (l == 2) ? x3 : (u16*)nullptr);
    }

    k_pool1<<<dim3(NG, NSL), dim3(256), 0, stream>>>(x4, x1, x2, x3, startg, endg, partial);
    k_final<<<dim3(NG), dim3(256), 0, stream>>>(partial, w_mlp1, b_mlp1, bn_g, bn_b, w_mlp2, b_mlp2, out);
}

// Round 14
// 324.925 us; speedup vs baseline: 1.1123x; 1.1123x over previous
//
#include <hip/hip_runtime.h>
#include <hip/hip_bf16.h>

#define NN 50000
#define NE 800000
#define NG 50
#define NSL 16    // pool slices per graph
#define NSCB 196  // scan blocks (196*256 = 50176 >= NN+1 nodes)
#define NNP (NSCB * 256)        // padded node count 50176
#define NC8 (NNP * 8)           // cnt8/excl8 size 401408

typedef unsigned short u16;
typedef unsigned int u32;
typedef __attribute__((ext_vector_type(8))) short short8;
typedef __attribute__((ext_vector_type(4))) float float4v;
typedef __attribute__((ext_vector_type(2))) float f32x2;

__device__ __forceinline__ float b2f(u16 u) {
    union { u32 i; float f; } v; v.i = ((u32)u) << 16; return v.f;
}
__device__ __forceinline__ u16 f2b(float f) {
    union { float f; u32 i; } v; v.f = f;
    u32 i = v.i;
    return (u16)((i + 0x7FFFu + ((i >> 16) & 1u)) >> 16);
}
__device__ __forceinline__ float lo16f(u32 u) { union { u32 i; float f; } v; v.i = u << 16; return v.f; }
__device__ __forceinline__ float hi16f(u32 u) { union { u32 i; float f; } v; v.i = u & 0xffff0000u; return v.f; }

// ---------------- init + detect + gaussian-coef precompute ----------------
struct SgP { const float* mu[4]; const float* sg[4]; };
__global__ void k_init(const int* __restrict__ ei_raw, int* flag,
                       int* cnt8, int* startg, int* endg, SgP S, float* __restrict__ gcoef,
                       int* dcnt) {
    __shared__ int cs[256];
    int i = blockIdx.x * blockDim.x + threadIdx.x;
    if (i < NC8) cnt8[i] = 0;
    if (i < NG) { startg[i] = 0x7fffffff; endg[i] = 0; }
    if (blockIdx.x == 2 && threadIdx.x < 64) dcnt[threadIdx.x] = 0;
    if (blockIdx.x == 0 && threadIdx.x < 64) {
        int t = threadIdx.x;          // [l][k][d] coef then [l][k][d] mu
        int l = (t >> 3) & 3, kd = t & 7;
        if (t < 32) {
            float s = S.sg[l][kd];
            gcoef[t] = -0.5f / (1e-15f + s * s);
        } else {
            gcoef[t] = S.mu[l][kd];   // gcoef[32 + l*8 + kd]
        }
    }
    if (blockIdx.x == 1) {
        int t = threadIdx.x;
        cs[t] = (ei_raw[2 * t + 1] == 0) ? 1 : 0;   // flag=1 <=> int64 edge_index
        __syncthreads();
        for (int d = 128; d > 0; d >>= 1) {
            if (t < d) cs[t] += cs[t + d];
            __syncthreads();
        }
        if (t == 0) *flag = (cs[0] >= 128) ? 1 : 0;
    }
}

// ---------------- cvt + prep mega-fusion: rank-hist | x2b(vec4) | wprep | bounds ----------------
// R14: reverted to R12's 1-edge/thread hist (R13's 2-edge version halved atomic parallelism
// and chained dependent atomics -> +33us regression).
struct WParams { const float* g[4]; const float* rw[4]; };
__global__ void k_cvtprep(const int* __restrict__ ei_raw, const int* __restrict__ batch_raw,
                          const int* __restrict__ flag, int* cnt8, u16* __restrict__ rank,
                          const float* __restrict__ x, u16* __restrict__ xb,
                          WParams P, u16* __restrict__ bsw,
                          int* startg, int* endg) {
    int b = blockIdx.x, t = threadIdx.x;
    if (b < 3125) {                        // rank histogram: color = src/6250 (src-range shard)
        int e = b * 256 + t;
        int w = *flag;
        int s = w ? ei_raw[2 * e] : ei_raw[e];
        int d = w ? ei_raw[2 * (NE + e)] : ei_raw[NE + e];
        int color = s / 6250;              // 0..7
        rank[e] = (u16)atomicAdd(&cnt8[d * 8 + color], 1);
    } else if (b < 6250) {                 // x2b vec4: 800000 threads x 4 elems = NN*64
        int i = (b - 3125) * 256 + t;      // exact fit: 3125*256*4 == NN*64
        float4 v = *(const float4*)(x + (size_t)i * 4);
        u32 lo = (u32)f2b(v.x) | ((u32)f2b(v.y) << 16);
        u32 hi = (u32)f2b(v.z) | ((u32)f2b(v.w) << 16);
        uint2 pk; pk.x = lo; pk.y = hi;
        *(uint2*)(xb + (size_t)i * 4) = pk;
    } else if (b < 6570) {                 // wprep: 4*20480 ids (320 blocks exact)
        int id = (b - 6250) * 256 + t;
        if (id < 4 * 20480) {
            int l = id / 20480, r = id % 20480;
            int j = r & 7, lane = (r >> 3) & 63, ctkt = r >> 9;
            int ct = ctkt & 3, kt = ctkt >> 2;
            int k = kt * 32 + (lane >> 4) * 8 + j;
            int n = ct * 16 + (lane & 15);
            float v;
            if (k < 256) v = P.g[l][(k & 63) * 256 + (k >> 6) * 64 + n];
            else         v = P.rw[l][(k - 256) * 64 + n];
            bsw[id] = f2b(v);
        }
    } else {                               // bounds: boundary scan on raw batch
        int n = (b - 6570) * 256 + t;
        if (n >= NN) return;
        int w = *flag;
        int bb = w ? batch_raw[2 * n] : batch_raw[n];
        if (n == 0) {
            startg[bb] = 0;
        } else {
            int bp = w ? batch_raw[2 * (n - 1)] : batch_raw[n - 1];
            if (bp != bb) { startg[bb] = n; endg[bp] = n; }
        }
        if (n == NN - 1) endg[bb] = NN;
    }
}

// ---------------- scan A: per-node color scan + degree-bucket rank (two-level) ----------------
__global__ __launch_bounds__(256) void k_scanA(const int* __restrict__ cnt8, int* __restrict__ excl8,
                                               int* __restrict__ bsum, int* dcnt, int* __restrict__ pnr) {
    __shared__ int s[256];
    __shared__ int hcnt[64];
    __shared__ int hbase[64];
    int t = threadIdx.x, b = blockIdx.x;
    int n = b * 256 + t;                  // node (padded)
    uint4 c0 = *(const uint4*)(cnt8 + (size_t)n * 8);
    uint4 c1 = *(const uint4*)(cnt8 + (size_t)n * 8 + 4);
    int v = c0.x + c0.y + c0.z + c0.w + c1.x + c1.y + c1.z + c1.w;
    if (t < 64) hcnt[t] = 0;
    s[t] = v; __syncthreads();
    for (int d = 1; d < 256; d <<= 1) {
        int x = s[t];
        int y = (t >= d) ? s[t - d] : 0;
        __syncthreads();
        s[t] = x + y;
        __syncthreads();
    }
    int run = s[t] - v;                   // exclusive prefix within block
    uint4 e0, e1;
    e0.x = run;            e0.y = run + c0.x;
    e0.z = e0.y + c0.y;    e0.w = e0.z + c0.z;
    e1.x = e0.w + c0.w;    e1.y = e1.x + c1.x;
    e1.z = e1.y + c1.y;    e1.w = e1.z + c1.z;
    *(uint4*)(excl8 + (size_t)n * 8) = e0;
    *(uint4*)(excl8 + (size_t)n * 8 + 4) = e1;
    if (t == 255) bsum[b] = s[255];
    // --- degree bucket rank ---
    int nb;
    if (n < NN) { nb = (v + 3) >> 2; if (nb > 62) nb = 62; } else nb = 63;
    int lrank = atomicAdd(&hcnt[nb], 1);
    __syncthreads();
    if (t < 64) hbase[t] = atomicAdd(&dcnt[t], hcnt[t]);
    __syncthreads();
    pnr[n] = (nb << 20) | (hbase[nb] + lrank);
}

// ---------------- scan B+C fused + perm scatter ----------------
__global__ __launch_bounds__(256) void k_scanBC(const int* __restrict__ excl8,
                                                const int* __restrict__ bsum,
                                                int* __restrict__ off8,
                                                const int* __restrict__ dcnt,
                                                const int* __restrict__ pnr,
                                                int* __restrict__ perm) {
    __shared__ int s[256];
    __shared__ int dsc[64];
    int t = threadIdx.x, b = blockIdx.x;
    int v = (t < NSCB) ? bsum[t] : 0;
    s[t] = v;
    if (t < 64) dsc[t] = dcnt[t];
    __syncthreads();
    for (int d = 1; d < 256; d <<= 1) {
        int x = s[t];
        int y = (t >= d) ? s[t - d] : 0;
        __syncthreads();
        s[t] = x + y;
        __syncthreads();
    }
    int ebase = (b == 0) ? 0 : s[b - 1];
    int n = b * 256 + t;
    uint4 e0 = *(const uint4*)(excl8 + (size_t)n * 8);
    uint4 e1 = *(const uint4*)(excl8 + (size_t)n * 8 + 4);
    e0.x += ebase; e0.y += ebase; e0.z += ebase; e0.w += ebase;
    e1.x += ebase; e1.y += ebase; e1.z += ebase; e1.w += ebase;
    *(uint4*)(off8 + (size_t)n * 8) = e0;
    *(uint4*)(off8 + (size_t)n * 8 + 4) = e1;
    // --- exclusive scan of 64 bucket counts (identical in every block) + scatter perm ---
    if (t == 0) {
        int runb = 0;
        for (int i = 0; i < 64; i++) { int c = dsc[i]; dsc[i] = runb; runb += c; }
    }
    __syncthreads();
    int pv = pnr[n];
    perm[dsc[pv >> 20] + (pv & 0xFFFFF)] = n;
}

// ---------------- scatter: ONE 8B record per edge: {src*128, a0q|a1q<<16} ----------------
// R14: keeps R12's 1-edge/thread structure; only change vs R12 is rec8.x = src BYTE offset
// (src*128) so aggemm's gather address is a single add (no 32->64 extend+shift).
__global__ void k_scatter(const int* __restrict__ ei_raw, const int* __restrict__ flag,
                          const int* __restrict__ off8, const u16* __restrict__ rank,
                          const float2* __restrict__ eattr2,
                          uint2* __restrict__ rec8) {
    int e = blockIdx.x * blockDim.x + threadIdx.x;
    if (e >= NE) return;
    int w = *flag;
    int s = w ? ei_raw[2 * e] : ei_raw[e];
    int d = w ? ei_raw[2 * (NE + e)] : ei_raw[NE + e];
    int color = s / 6250;                 // matches k_cvtprep's color
    int slot = off8[d * 8 + color] + (int)rank[e];
    float2 at = eattr2[e];
    u32 q0 = (u32)(fminf(fmaxf(at.x, 0.f), 1.f) * 65535.f + 0.5f);
    u32 q1 = (u32)(fminf(fmaxf(at.y, 0.f), 1.f) * 65535.f + 0.5f);
    uint2 r; r.x = (u32)s * 128u; r.y = q0 | (q1 << 16);
    rec8[slot] = r;
}

// ---------------- weights: once-per-edge gaussian weights from rec8, fully coalesced ----------------
__global__ __launch_bounds__(256) void k_wgts(const uint2* __restrict__ rec8,
                                              const float* __restrict__ gcoef,
                                              uint2* __restrict__ agw) {
    int j = blockIdx.x * blockDim.x + threadIdx.x;
    if (j >= NE) return;
    uint2 r = rec8[j];
    float a0 = (float)(r.y & 0xffffu) * (1.0f / 65535.0f);
    float a1 = (float)(r.y >> 16) * (1.0f / 65535.0f);
#pragma unroll
    for (int l = 0; l < 4; l++) {
        u16 wq[4];
#pragma unroll
        for (int k = 0; k < 4; k++) {
            float m0 = gcoef[32 + l * 8 + 2 * k], m1 = gcoef[32 + l * 8 + 2 * k + 1];
            float c0 = gcoef[l * 8 + 2 * k],      c1 = gcoef[l * 8 + 2 * k + 1];
            float d0 = a0 - m0, d1 = a1 - m1;
            float t = d0 * d0 * c0 + d1 * d1 * c1;   // t <= 0, c includes -0.5
            wq[k] = f2b(__expf(t));
        }
        uint2 o;
        o.x = (u32)wq[0] | ((u32)wq[1] << 16);
        o.y = (u32)wq[2] | ((u32)wq[3] << 16);
        agw[(size_t)l * NE + j] = o;
    }
}

// ---------------- fused aggregation + GEMM (R12 structure + byte-offset gather) ----------------
// R13's per-iteration fast/tail branch regressed (code bloat defeats the compiler schedule);
// R14 restores R12's single clamped-tail loop. Only delta vs R12: rec8.x is a byte offset.
#define LDA 328  // 320 + 8 u16 pad -> rows 656B, 16B aligned
#define ROWS 32
__global__ __launch_bounds__(512, 8) void k_aggemm(const u16* __restrict__ xin,
                                                   const uint2* __restrict__ rec8,
                                                   const uint2* __restrict__ agw,
                                                   const int* __restrict__ off8,
                                                   const int* __restrict__ perm,
                                                   const u16* __restrict__ bsw,
                                                   const float* __restrict__ bias,
                                                   u16* __restrict__ xout,
                                                   const u16* __restrict__ xadd,
                                                   u16* __restrict__ x3out) {
    __shared__ u16 As[ROWS * LDA];
    int t = threadIdx.x;
    int rbase = blockIdx.x * ROWS;
    int wave = t >> 6, lane = t & 63;
    int sub = lane >> 4;      // node sub-group 0..3
    int f = lane & 15;        // feature quad: features 4f..4f+3

    // stage the 32 xin rows (concat part, cols 256..319) — row-gathered via perm
    if (t < 256) {
        int row = t >> 3, pos = t & 7;
        int grow = perm[rbase + row];
        uint4 v = make_uint4(0, 0, 0, 0);
        if (grow < NN) v = *(const uint4*)(xin + (size_t)grow * 64 + pos * 8);
        *(uint4*)(&As[row * LDA + 256 + pos * 8]) = v;
    }

    // ---- phase A: each 16-lane sub-group aggregates its node into As[row][0..255] ----
    {
        int row = (wave << 2) + sub;
        int wid = perm[rbase + row];      // deg-sorted node id; pads (>=NN) have beg==end
        int beg = off8[wid * 8], end = off8[wid * 8 + 8];
        int endm1 = end - 1;
        f32x2 acc[4][2];                  // [k][pair]: this lane's feats 4f..4f+3, all 4 k's
#pragma unroll
        for (int k = 0; k < 4; k++) {
            acc[k][0] = (f32x2){0.f, 0.f};
            acc[k][1] = (f32x2){0.f, 0.f};
        }
        int nb = (end - beg + 3) >> 2;    // 4 edges per batch per node
        for (int bt = 0; bt < nb; bt++) {
            int j0 = beg + bt * 4;
            u32 s[4]; uint2 wv[4];
#pragma unroll
            for (int u = 0; u < 4; u++) {     // phase 1: broadcast rec loads (clamped tail)
                int j = j0 + u;
                int jc = j < endm1 ? j : endm1;
                bool ok = j < end;
                s[u] = rec8[jc].x;
                uint2 w = agw[jc];
                wv[u].x = ok ? w.x : 0u;      // zero weight kills tail contribution
                wv[u].y = ok ? w.y : 0u;
            }
            uint2 xr[4];
#pragma unroll
            for (int u = 0; u < 4; u++)       // phase 2: all x gathers issue together
                xr[u] = *(const uint2*)((const char*)xin + (size_t)s[u] + f * 8);
#pragma unroll
            for (int u = 0; u < 4; u++) {     // phase 3: FMAs (weights pre-packed bf16)
                f32x2 x01, x23;
                x01.x = lo16f(xr[u].x); x01.y = hi16f(xr[u].x);
                x23.x = lo16f(xr[u].y); x23.y = hi16f(xr[u].y);
                float w0 = lo16f(wv[u].x), w1 = hi16f(wv[u].x);
                float w2 = lo16f(wv[u].y), w3 = hi16f(wv[u].y);
                acc[0][0] += w0 * x01; acc[0][1] += w0 * x23;
                acc[1][0] += w1 * x01; acc[1][1] += w1 * x23;
                acc[2][0] += w2 * x01; acc[2][1] += w2 * x23;
                acc[3][0] += w3 * x01; acc[3][1] += w3 * x23;
            }
        }
        int deg = end - beg;
        float sc = 1.0f / (float)(deg > 1 ? deg : 1);
#pragma unroll
        for (int k = 0; k < 4; k++) {
            u16 o0 = f2b(acc[k][0].x * sc), o1 = f2b(acc[k][0].y * sc);
            u16 o2 = f2b(acc[k][1].x * sc), o3 = f2b(acc[k][1].y * sc);
            uint2 pk;
            pk.x = (u32)o0 | ((u32)o1 << 16);
            pk.y = (u32)o2 | ((u32)o3 << 16);
            *(uint2*)(&As[row * LDA + k * 64 + f * 4]) = pk;   // k-major [k*64+feat]
        }
    }
    __syncthreads();

    // ---- phase B: xout = lrelu(As(32,320) @ Wcat(320,64) + b); opt x3 = x0 + xout ----
    // 8 waves -> one 16x16 C tile each: rt = wave&1 (row tile), ct = wave>>1 (col tile)
    int lr = lane & 15, lg = lane >> 4;
    int rt = wave & 1;
    int ct = wave >> 1;
    const u16* ar = &As[(rt * 16 + lr) * LDA + lg * 8];
    const uint4* bp = (const uint4*)bsw;
    float4v acc0 = {0.f, 0.f, 0.f, 0.f};
    for (int kt = 0; kt < 10; kt++) {
        short8 a  = *(const short8*)(ar + kt * 32);
        short8 b0 = *(const short8*)(bp + (kt * 4 + ct) * 64 + lane);
        acc0 = __builtin_amdgcn_mfma_f32_16x16x32_bf16(a, b0, acc0, 0, 0, 0);
    }
    {
        int col = ct * 16 + lr;
        float bv = bias[col];
#pragma unroll
        for (int reg = 0; reg < 4; reg++) {
            int grow = perm[rbase + rt * 16 + lg * 4 + reg];  // C/D: row=(lane>>4)*4+reg
            if (grow < NN) {
                float v = acc0[reg] + bv;
                v = v > 0.f ? v : 0.01f * v;
                xout[(size_t)grow * 64 + col] = f2b(v);
                if (x3out) {
                    float s2 = v + b2f(xadd[(size_t)grow * 64 + col]);
                    x3out[(size_t)grow * 64 + col] = f2b(s2);
                }
            }
        }
    }
}

// ---------------- pool stage 1: partial max over node slice, concat [x4,x1,x2,x3] ----------------
__global__ __launch_bounds__(256) void k_pool1(const u16* __restrict__ x4, const u16* __restrict__ x1,
                                               const u16* __restrict__ x2, const u16* __restrict__ x3,
                                               const int* __restrict__ startg, const int* __restrict__ endg,
                                               float* __restrict__ partial) {
    int g = blockIdx.x, sl = blockIdx.y;
    int c = threadIdx.x;
    const u16* arr = (c < 64) ? x4 : (c < 128) ? x1 : (c < 192) ? x2 : x3;
    int h = c & 63;
    int s = startg[g], e = endg[g];
    int len = e - s;
    int chunk = (len + NSL - 1) / NSL;
    int s0 = s + sl * chunk;
    int e0 = s0 + chunk; if (e0 > e) e0 = e;
    float m = -3.4e38f;
    for (int n = s0; n < e0; n++) {
        float v = b2f(arr[(size_t)n * 64 + h]);
        m = v > m ? v : m;
    }
    partial[((size_t)g * NSL + sl) * 256 + c] = m;
}

// ---------------- final MLP fused with pool stage 2 (256 thr, split-j reduce) ----------------
__global__ __launch_bounds__(256) void k_final(const float* __restrict__ partial, const float* __restrict__ w1,
                        const float* __restrict__ b1, const float* __restrict__ gamma,
                        const float* __restrict__ beta, const float* __restrict__ w2,
                        const float* __restrict__ b2v, float* __restrict__ out) {
    __shared__ float pld[256];
    __shared__ float part[256];
    __shared__ float zsh[64];
    int g = blockIdx.x, t = threadIdx.x;
    int h = t & 63, jq = t >> 6;
    {
        float m = -3.4e38f;
#pragma unroll
        for (int sl = 0; sl < NSL; sl++) {
            float v = partial[((size_t)g * NSL + sl) * 256 + t];
            m = v > m ? v : m;
        }
        pld[t] = m;
    }
    __syncthreads();
    float z = 0.f;
    for (int j = jq * 64; j < jq * 64 + 64; j++) z += pld[j] * w1[j * 64 + h];
    part[t] = z;
    __syncthreads();
    if (t < 64) {
        float zz = b1[t] + part[t] + part[64 + t] + part[128 + t] + part[192 + t];
        zz = zz * 0.9999950000374997f * gamma[t] + beta[t];  // /sqrt(1+1e-5)
        zz = zz > 0.f ? zz : 0.f;
        zsh[t] = zz;
    }
    __syncthreads();
    if (t < 10) {
        float o = b2v[t];
        for (int k = 0; k < 64; k++) o += zsh[k] * w2[k * 10 + t];
        out[g * 10 + t] = o;   // fp32 output
    }
}

extern "C" void kernel_launch(void* const* d_in, const int* in_sizes, int n_in,
                              void* d_out, int out_size, void* d_ws, size_t ws_size,
                              hipStream_t stream) {
    const float* x_in    = (const float*)d_in[0];
    const int* ei_raw    = (const int*)d_in[1];
    const int* batch_raw = (const int*)d_in[2];
    const float* eattr   = (const float*)d_in[3];

    const float *g_[4], *mu_[4], *sg_[4], *rw_[4], *b_[4];
    for (int i = 0; i < 4; i++) {
        g_[i]  = (const float*)d_in[4 + 5 * i + 0];
        mu_[i] = (const float*)d_in[4 + 5 * i + 1];
        sg_[i] = (const float*)d_in[4 + 5 * i + 2];
        rw_[i] = (const float*)d_in[4 + 5 * i + 3];
        b_[i]  = (const float*)d_in[4 + 5 * i + 4];
    }
    const float* w_mlp1 = (const float*)d_in[24];
    const float* b_mlp1 = (const float*)d_in[25];
    const float* bn_g   = (const float*)d_in[26];
    const float* bn_b   = (const float*)d_in[27];
    const float* w_mlp2 = (const float*)d_in[28];
    const float* b_mlp2 = (const float*)d_in[29];
    float* out = (float*)d_out;

    // workspace carve-up (~51 MB)
    char* ws = (char*)d_ws;
    size_t o = 0;
    auto take = [&](size_t bytes) { size_t r = o; o += (bytes + 255) & ~(size_t)255; return r; };
    int*    flag     = (int*)(ws + take(4));
    float*  gcoef    = (float*)(ws + take(64 * 4));
    int*    dcnt     = (int*)(ws + take(64 * 4));
    u16*    rank     = (u16*)(ws + take((size_t)NE * 2));
    int*    cnt8     = (int*)(ws + take((size_t)NC8 * 4));
    int*    excl8    = (int*)(ws + take((size_t)NC8 * 4));
    int*    off8     = (int*)(ws + take((size_t)(NC8 + 8) * 4));
    int*    bsum     = (int*)(ws + take((size_t)NSCB * 4));
    int*    pnr      = (int*)(ws + take((size_t)NNP * 4));
    int*    perm     = (int*)(ws + take((size_t)NNP * 4));
    uint2*  rec8     = (uint2*)(ws + take((size_t)NE * 8));
    uint2*  agw      = (uint2*)(ws + take((size_t)4 * NE * 8));
    u16*    xb       = (u16*)(ws + take((size_t)NN * 64 * 2));
    u16*    x0       = (u16*)(ws + take((size_t)NN * 64 * 2));
    u16*    x1       = (u16*)(ws + take((size_t)NN * 64 * 2));
    u16*    x2       = (u16*)(ws + take((size_t)NN * 64 * 2));
    u16*    x3       = (u16*)(ws + take((size_t)NN * 64 * 2));
    u16*    x4       = (u16*)(ws + take((size_t)NN * 64 * 2));
    u16*    bsw      = (u16*)(ws + take((size_t)4 * 320 * 64 * 2));
    float*  partial  = (float*)(ws + take((size_t)NG * NSL * 256 * 4));
    int*    startg   = (int*)(ws + take(NG * 4));
    int*    endg     = (int*)(ws + take(NG * 4));
    (void)ws_size; (void)in_sizes; (void)n_in; (void)out_size;

    SgP SP;
    for (int i = 0; i < 4; i++) { SP.mu[i] = mu_[i]; SP.sg[i] = sg_[i]; }
    k_init<<<dim3((NC8 + 255) / 256), dim3(256), 0, stream>>>(ei_raw, flag, cnt8, startg, endg, SP, gcoef, dcnt);

    WParams WP;
    for (int i = 0; i < 4; i++) { WP.g[i] = g_[i]; WP.rw[i] = rw_[i]; }
    k_cvtprep<<<dim3(6766), dim3(256), 0, stream>>>(
        ei_raw, batch_raw, flag, cnt8, rank, x_in, xb, WP, bsw, startg, endg);

    k_scanA<<<dim3(NSCB), dim3(256), 0, stream>>>(cnt8, excl8, bsum, dcnt, pnr);
    k_scanBC<<<dim3(NSCB), dim3(256), 0, stream>>>(excl8, bsum, off8, dcnt, pnr, perm);
    k_scatter<<<dim3(NE / 256), dim3(256), 0, stream>>>(
        ei_raw, flag, off8, rank, (const float2*)eattr, rec8);
    k_wgts<<<dim3(NE / 256), dim3(256), 0, stream>>>(rec8, gcoef, agw);

    const int agGrid = NNP / ROWS;         // 1568 blocks over deg-sorted perm
    const u16* lin[4]  = {xb, x0, x1, x3};
    u16*       lout[4] = {x0, x1, x2, x4};
    for (int l = 0; l < 4; l++) {
        k_aggemm<<<dim3(agGrid), dim3(512), 0, stream>>>(
            lin[l], rec8, agw + (size_t)l * NE, off8, perm,
            bsw + (size_t)l * 20480, b_[l], lout[l],
            (l == 2) ? x0 : (const u16*)nullptr,
            (l == 2) ? x3 : (u16*)nullptr);
    }

    k_pool1<<<dim3(NG, NSL), dim3(256), 0, stream>>>(x4, x1, x2, x3, startg, endg, partial);
    k_final<<<dim3(NG), dim3(256), 0, stream>>>(partial, w_mlp1, b_mlp1, bn_g, bn_b, w_mlp2, b_mlp2, out);
}